// Round 4
// baseline (112.564 us; speedup 1.0000x reference)
//
#include <hip/hip_runtime.h>

#define IMG_W 256
#define IMG_H 256
#define N_PTS 320
#define VD 256
#define VH 256
#define VW 256
#define DSTEP (6.0f / (N_PTS - 1))
#define TPX 16   // pixels (w) per block
#define CPR 16   // chunk-threads per ray

// Fused clip + render. Block (TPX, CPR) = 256 thr; grid (IMG_W/TPX, IMG_H).
// Wave = 16 consecutive w-pixels x 4 chunk-rows -> x-adjacent gathers.
// No workspace, no atomics: out[] fully written here, normalized by kernel 2.
__global__ __launch_bounds__(256) void render_kernel(
    const float* __restrict__ vol,    // (256,256,256) z-major
    const float* __restrict__ Rm, const float* __restrict__ Tv,
    const float* __restrict__ focal,
    float* __restrict__ out)          // out[w*IMG_H + h] = unnormalized gray
{
    const int tx = threadIdx.x;              // 0..15 pixel-in-tile
    const int ty = threadIdx.y;              // 0..15 chunk
    const int w  = blockIdx.x * TPX + tx;
    const int h  = blockIdx.y;

    // --- ray coefficients (voxel space, affine in depth d) ---
    const float a  = 1.0f - 1.0f / IMG_W;
    const float gx = a - (2.0f * a / (IMG_W - 1)) * (float)w;
    const float gy = a - (2.0f * a / (IMG_H - 1)) * (float)h;
    const float f  = focal[0];
    const float ux = gx / f, uy = gy / f;
    const float R00 = Rm[0], R01 = Rm[1], R02 = Rm[2];
    const float R10 = Rm[3], R11 = Rm[4], R12 = Rm[5];
    const float R20 = Rm[6], R21 = Rm[7], R22 = Rm[8];
    const float Tx = Tv[0], Ty = Tv[1], Tz = Tv[2];
    const float Bx = R00 * ux + R01 * uy + R02;
    const float By = R10 * ux + R11 * uy + R12;
    const float Bz = R20 * ux + R21 * uy + R22;
    const float Ax = -(R00 * Tx + R01 * Ty + R02 * Tz);
    const float Ay = -(R10 * Tx + R11 * Ty + R12 * Tz);
    const float Az = -(R20 * Tx + R21 * Ty + R22 * Tz);
    const float voxel = 2.0f / 256.0f;
    const float hxe = voxel * (VW - 1) * 0.5f;
    const float hye = voxel * (VH - 1) * 0.5f;
    const float hze = voxel * (VD - 1) * 0.5f;
    const float sxc = 0.5f * (VW - 1) / hxe, oxc = 0.5f * (VW - 1);
    const float syc = 0.5f * (VH - 1) / hye, oyc = 0.5f * (VH - 1);
    const float szc = 0.5f * (VD - 1) / hze, ozc = 0.5f * (VD - 1);
    const float fBx = Bx * sxc, fAx = Ax * sxc + oxc;
    const float fBy = By * syc, fAy = Ay * syc + oyc;
    const float fBz = Bz * szc, fAz = Az * szc + ozc;

    // --- exact slab clip: contribution requires f{x,y,z} in [-1, 256) ---
    float dlo = 3.0f, dhi = 9.0f;
    {
        const float lo = -1.0f, hi = 256.0f;
        const float fA[3] = { fAx, fAy, fAz };
        const float fB[3] = { fBx, fBy, fBz };
        #pragma unroll
        for (int dim = 0; dim < 3; ++dim) {
            if (fabsf(fB[dim]) > 1e-12f) {
                const float r = 1.0f / fB[dim];
                const float t0 = (lo - fA[dim]) * r, t1 = (hi - fA[dim]) * r;
                dlo = fmaxf(dlo, fminf(t0, t1));
                dhi = fminf(dhi, fmaxf(t0, t1));
            } else if (fA[dim] < lo || fA[dim] >= hi) {
                dhi = -1.0f;
            }
        }
    }
    int pmin = 0, len = 0;
    if (dhi > dlo) {
        pmin = max(0, (int)floorf((dlo - 3.0f) / DSTEP) - 1);
        const int pmax = min(N_PTS, (int)ceilf((dhi - 3.0f) / DSTEP) + 2);
        len = max(0, pmax - pmin);
    }

    // dynamic chunking over the clipped range
    const int plo = pmin + ((len * ty) >> 4);
    const int phi = pmin + ((len * (ty + 1)) >> 4);

    float S = 0.0f, A = 1.0f;
    for (int p = plo; p < phi; ++p) {
        const float d = 3.0f + (float)p * DSTEP;
        const float fx = fmaf(fBx, d, fAx);
        const float fy = fmaf(fBy, d, fAy);
        const float fz = fmaf(fBz, d, fAz);

        const float flx = floorf(fx), fly = floorf(fy), flz = floorf(fz);
        const int ix0 = (int)flx, iy0 = (int)fly, iz0 = (int)flz;

        float dens = 0.0f, feat = 0.0f;
        if (ix0 >= -1 && ix0 < VW && iy0 >= -1 && iy0 < VH && iz0 >= -1 && iz0 < VD) {
            const float frx = fx - flx, fry = fy - fly, frz = fz - flz;
            float wx0 = 1.0f - frx, wx1 = frx;
            float wy0 = 1.0f - fry, wy1 = fry;
            float wz0 = 1.0f - frz, wz1 = frz;
            if (ix0 < 0)       wx0 = 0.0f;
            if (ix0 + 1 >= VW) wx1 = 0.0f;
            if (iy0 < 0)       wy0 = 0.0f;
            if (iy0 + 1 >= VH) wy1 = 0.0f;
            if (iz0 < 0)       wz0 = 0.0f;
            if (iz0 + 1 >= VD) wz1 = 0.0f;

            const int cx0 = max(ix0, 0), cx1 = min(ix0 + 1, VW - 1);
            const int cy0 = max(iy0, 0), cy1 = min(iy0 + 1, VH - 1);
            const int cz0 = max(iz0, 0), cz1 = min(iz0 + 1, VD - 1);

            const int zb0 = cz0 * (VH * VW), zb1 = cz1 * (VH * VW);
            const int yb0 = cy0 * VW,        yb1 = cy1 * VW;

            const float v000 = vol[zb0 + yb0 + cx0];
            const float v001 = vol[zb0 + yb0 + cx1];
            const float v010 = vol[zb0 + yb1 + cx0];
            const float v011 = vol[zb0 + yb1 + cx1];
            const float v100 = vol[zb1 + yb0 + cx0];
            const float v101 = vol[zb1 + yb0 + cx1];
            const float v110 = vol[zb1 + yb1 + cx0];
            const float v111 = vol[zb1 + yb1 + cx1];

            const float w00 = wy0 * wz0, w01 = wy1 * wz0;
            const float w10 = wy0 * wz1, w11 = wy1 * wz1;
            const float c000 = wx0 * w00, c001 = wx1 * w00;
            const float c010 = wx0 * w01, c011 = wx1 * w01;
            const float c100 = wx0 * w10, c101 = wx1 * w10;
            const float c110 = wx0 * w11, c111 = wx1 * w11;

            feat = c000 * v000 + c001 * v001 + c010 * v010 + c011 * v011
                 + c100 * v100 + c101 * v101 + c110 * v110 + c111 * v111;
            dens = 0.1f * (c000 + c001 + c010 + c011 + c100 + c101 + c110 + c111);
        }

        S = fmaf(dens * A, feat, S);   // (1 + 1e-10) rounds to 1.0f
        A *= (1.0f - dens);
    }

    __shared__ float lS[CPR][TPX];
    __shared__ float lA[CPR][TPX];
    lS[ty][tx] = S;
    lA[ty][tx] = A;
    __syncthreads();

    if (ty == 0) {
        float Stot = 0.0f, Atot = 1.0f;
        #pragma unroll
        for (int c = 0; c < CPR; ++c) {
            Stot = fmaf(Atot, lS[c][tx], Stot);
            Atot *= lA[c][tx];
        }
        const float gray = (3.0f * Stot + (1.0f - Atot)) * 0.25f;
        out[w * IMG_H + h] = gray;   // empty ray => exactly 0
    }
}

// Single-block fused max + normalize: 1024 threads, 64 floats each (float4 x16).
__global__ __launch_bounds__(1024) void maxnorm_kernel(float* __restrict__ out)
{
    float4* o4 = (float4*)out;
    const int tid = threadIdx.x;            // 0..1023
    const int NV4 = (IMG_W * IMG_H) / 4;    // 16384

    float4 v[16];
    float m = 0.0f;                          // gray >= 0 always
    #pragma unroll
    for (int k = 0; k < 16; ++k) {
        v[k] = o4[tid + k * 1024];
        m = fmaxf(m, fmaxf(fmaxf(v[k].x, v[k].y), fmaxf(v[k].z, v[k].w)));
    }

    // wave (64) reduce
    #pragma unroll
    for (int off = 32; off > 0; off >>= 1)
        m = fmaxf(m, __shfl_down(m, off));

    __shared__ float lm[16];
    if ((tid & 63) == 0) lm[tid >> 6] = m;
    __syncthreads();
    if (tid == 0) {
        float mm = lm[0];
        #pragma unroll
        for (int i = 1; i < 16; ++i) mm = fmaxf(mm, lm[i]);
        lm[0] = mm;
    }
    __syncthreads();
    const float inv = 1.0f / (lm[0] + 1e-8f);

    #pragma unroll
    for (int k = 0; k < 16; ++k) {
        float4 r;
        r.x = (v[k].x + 1e-8f) * inv;
        r.y = (v[k].y + 1e-8f) * inv;
        r.z = (v[k].z + 1e-8f) * inv;
        r.w = (v[k].w + 1e-8f) * inv;
        o4[tid + k * 1024] = r;
    }
    (void)NV4;
}

extern "C" void kernel_launch(void* const* d_in, const int* in_sizes, int n_in,
                              void* d_out, int out_size, void* d_ws, size_t ws_size,
                              hipStream_t stream) {
    (void)in_sizes; (void)n_in; (void)out_size; (void)d_ws; (void)ws_size;
    const float* vol   = (const float*)d_in[0];
    const float* Rm    = (const float*)d_in[1];
    const float* Tv    = (const float*)d_in[2];
    const float* focal = (const float*)d_in[3];
    float* out = (float*)d_out;

    dim3 rblock(TPX, CPR, 1);
    dim3 rgrid(IMG_W / TPX, IMG_H, 1);
    render_kernel<<<rgrid, rblock, 0, stream>>>(vol, Rm, Tv, focal, out);

    maxnorm_kernel<<<1, 1024, 0, stream>>>(out);
}

// Round 5
// 109.039 us; speedup vs baseline: 1.0323x; 1.0323x over previous
//
#include <hip/hip_runtime.h>

#define IMG_W 256
#define IMG_H 256
#define N_PTS 320
#define VD 256
#define VH 256
#define VW 256
#define DSTEP (6.0f / (N_PTS - 1))
#define TPX 16   // pixels (w) per block
#define CPR 16   // chunk-threads per ray
#define NBLK (IMG_W / TPX * IMG_H)   // 4096 render blocks

// ws layout (float*): [0 .. NBLK) per-render-block max (every slot written)

// Fused clip + render. Block (TPX, CPR) = 256 thr; grid (IMG_W/TPX, IMG_H).
__global__ __launch_bounds__(256) void render_kernel(
    const float* __restrict__ vol,    // (256,256,256) z-major
    const float* __restrict__ Rm, const float* __restrict__ Tv,
    const float* __restrict__ focal,
    float* __restrict__ out,          // out[w*IMG_H + h] = unnormalized gray
    float* __restrict__ blkmax)       // [NBLK]
{
    const int tx = threadIdx.x;              // 0..15 pixel-in-tile
    const int ty = threadIdx.y;              // 0..15 chunk
    const int w  = blockIdx.x * TPX + tx;
    const int h  = blockIdx.y;

    // --- ray coefficients (voxel space, affine in depth d) ---
    const float a  = 1.0f - 1.0f / IMG_W;
    const float gx = a - (2.0f * a / (IMG_W - 1)) * (float)w;
    const float gy = a - (2.0f * a / (IMG_H - 1)) * (float)h;
    const float f  = focal[0];
    const float ux = gx / f, uy = gy / f;
    const float R00 = Rm[0], R01 = Rm[1], R02 = Rm[2];
    const float R10 = Rm[3], R11 = Rm[4], R12 = Rm[5];
    const float R20 = Rm[6], R21 = Rm[7], R22 = Rm[8];
    const float Tx = Tv[0], Ty = Tv[1], Tz = Tv[2];
    const float Bx = R00 * ux + R01 * uy + R02;
    const float By = R10 * ux + R11 * uy + R12;
    const float Bz = R20 * ux + R21 * uy + R22;
    const float Ax = -(R00 * Tx + R01 * Ty + R02 * Tz);
    const float Ay = -(R10 * Tx + R11 * Ty + R12 * Tz);
    const float Az = -(R20 * Tx + R21 * Ty + R22 * Tz);
    const float voxel = 2.0f / 256.0f;
    const float hxe = voxel * (VW - 1) * 0.5f;
    const float hye = voxel * (VH - 1) * 0.5f;
    const float hze = voxel * (VD - 1) * 0.5f;
    const float sxc = 0.5f * (VW - 1) / hxe, oxc = 0.5f * (VW - 1);
    const float syc = 0.5f * (VH - 1) / hye, oyc = 0.5f * (VH - 1);
    const float szc = 0.5f * (VD - 1) / hze, ozc = 0.5f * (VD - 1);
    const float fBx = Bx * sxc, fAx = Ax * sxc + oxc;
    const float fBy = By * syc, fAy = Ay * syc + oyc;
    const float fBz = Bz * szc, fAz = Az * szc + ozc;

    // --- exact slab clip: contribution requires f{x,y,z} in [-1, 256) ---
    float dlo = 3.0f, dhi = 9.0f;
    {
        const float lo = -1.0f, hi = 256.0f;
        const float fA[3] = { fAx, fAy, fAz };
        const float fB[3] = { fBx, fBy, fBz };
        #pragma unroll
        for (int dim = 0; dim < 3; ++dim) {
            if (fabsf(fB[dim]) > 1e-12f) {
                const float r = 1.0f / fB[dim];
                const float t0 = (lo - fA[dim]) * r, t1 = (hi - fA[dim]) * r;
                dlo = fmaxf(dlo, fminf(t0, t1));
                dhi = fminf(dhi, fmaxf(t0, t1));
            } else if (fA[dim] < lo || fA[dim] >= hi) {
                dhi = -1.0f;
            }
        }
    }
    int pmin = 0, len = 0;
    if (dhi > dlo) {
        pmin = max(0, (int)floorf((dlo - 3.0f) / DSTEP) - 1);
        const int pmax = min(N_PTS, (int)ceilf((dhi - 3.0f) / DSTEP) + 2);
        len = max(0, pmax - pmin);
    }

    // dynamic chunking over the clipped range
    const int plo = pmin + ((len * ty) >> 4);
    const int phi = pmin + ((len * (ty + 1)) >> 4);

    float S = 0.0f, A = 1.0f;
    for (int p = plo; p < phi; ++p) {
        const float d = 3.0f + (float)p * DSTEP;
        const float fx = fmaf(fBx, d, fAx);
        const float fy = fmaf(fBy, d, fAy);
        const float fz = fmaf(fBz, d, fAz);

        const float flx = floorf(fx), fly = floorf(fy), flz = floorf(fz);
        const int ix0 = (int)flx, iy0 = (int)fly, iz0 = (int)flz;

        float dens = 0.0f, feat = 0.0f;
        if (ix0 >= -1 && ix0 < VW && iy0 >= -1 && iy0 < VH && iz0 >= -1 && iz0 < VD) {
            const float frx = fx - flx, fry = fy - fly, frz = fz - flz;
            float wx0 = 1.0f - frx, wx1 = frx;
            float wy0 = 1.0f - fry, wy1 = fry;
            float wz0 = 1.0f - frz, wz1 = frz;
            if (ix0 < 0)       wx0 = 0.0f;
            if (ix0 + 1 >= VW) wx1 = 0.0f;
            if (iy0 < 0)       wy0 = 0.0f;
            if (iy0 + 1 >= VH) wy1 = 0.0f;
            if (iz0 < 0)       wz0 = 0.0f;
            if (iz0 + 1 >= VD) wz1 = 0.0f;

            const int cx0 = max(ix0, 0), cx1 = min(ix0 + 1, VW - 1);
            const int cy0 = max(iy0, 0), cy1 = min(iy0 + 1, VH - 1);
            const int cz0 = max(iz0, 0), cz1 = min(iz0 + 1, VD - 1);

            const int zb0 = cz0 * (VH * VW), zb1 = cz1 * (VH * VW);
            const int yb0 = cy0 * VW,        yb1 = cy1 * VW;

            const float v000 = vol[zb0 + yb0 + cx0];
            const float v001 = vol[zb0 + yb0 + cx1];
            const float v010 = vol[zb0 + yb1 + cx0];
            const float v011 = vol[zb0 + yb1 + cx1];
            const float v100 = vol[zb1 + yb0 + cx0];
            const float v101 = vol[zb1 + yb0 + cx1];
            const float v110 = vol[zb1 + yb1 + cx0];
            const float v111 = vol[zb1 + yb1 + cx1];

            const float w00 = wy0 * wz0, w01 = wy1 * wz0;
            const float w10 = wy0 * wz1, w11 = wy1 * wz1;
            const float c000 = wx0 * w00, c001 = wx1 * w00;
            const float c010 = wx0 * w01, c011 = wx1 * w01;
            const float c100 = wx0 * w10, c101 = wx1 * w10;
            const float c110 = wx0 * w11, c111 = wx1 * w11;

            feat = c000 * v000 + c001 * v001 + c010 * v010 + c011 * v011
                 + c100 * v100 + c101 * v101 + c110 * v110 + c111 * v111;
            dens = 0.1f * (c000 + c001 + c010 + c011 + c100 + c101 + c110 + c111);
        }

        S = fmaf(dens * A, feat, S);   // (1 + 1e-10) rounds to 1.0f
        A *= (1.0f - dens);
    }

    __shared__ float lS[CPR][TPX];
    __shared__ float lA[CPR][TPX];
    lS[ty][tx] = S;
    lA[ty][tx] = A;
    __syncthreads();

    if (ty == 0) {
        float Stot = 0.0f, Atot = 1.0f;
        #pragma unroll
        for (int c = 0; c < CPR; ++c) {
            Stot = fmaf(Atot, lS[c][tx], Stot);
            Atot *= lA[c][tx];
        }
        const float gray = (3.0f * Stot + (1.0f - Atot)) * 0.25f;
        out[w * IMG_H + h] = gray;   // empty ray => exactly 0

        // block max over the 16 ty==0 lanes; every block WRITES its slot
        float m = gray;
        m = fmaxf(m, __shfl_down(m, 8));
        m = fmaxf(m, __shfl_down(m, 4));
        m = fmaxf(m, __shfl_down(m, 2));
        m = fmaxf(m, __shfl_down(m, 1));
        if (tx == 0)
            blkmax[blockIdx.y * gridDim.x + blockIdx.x] = m;
    }
}

// 64 blocks x 256 threads. Each block: reduce the 4096 blkmax entries
// (redundantly, ~16 KB/block from L2), then normalize its 1024-float slice.
__global__ __launch_bounds__(256) void normalize_kernel(
    float* __restrict__ out, const float* __restrict__ blkmax)
{
    const int tid = threadIdx.x;

    float m = 0.0f;
    #pragma unroll
    for (int k = 0; k < NBLK / 256; ++k)        // 16 strided reads
        m = fmaxf(m, blkmax[tid + k * 256]);

    #pragma unroll
    for (int off = 32; off > 0; off >>= 1)
        m = fmaxf(m, __shfl_down(m, off));

    __shared__ float lm[4];
    if ((tid & 63) == 0) lm[tid >> 6] = m;
    __syncthreads();
    const float mm = fmaxf(fmaxf(lm[0], lm[1]), fmaxf(lm[2], lm[3]));
    const float inv = 1.0f / (mm + 1e-8f);

    float4* o4 = (float4*)out;
    const int i = blockIdx.x * 256 + tid;       // 16384 float4 total
    float4 v = o4[i];
    v.x = (v.x + 1e-8f) * inv;
    v.y = (v.y + 1e-8f) * inv;
    v.z = (v.z + 1e-8f) * inv;
    v.w = (v.w + 1e-8f) * inv;
    o4[i] = v;
}

extern "C" void kernel_launch(void* const* d_in, const int* in_sizes, int n_in,
                              void* d_out, int out_size, void* d_ws, size_t ws_size,
                              hipStream_t stream) {
    (void)in_sizes; (void)n_in; (void)out_size; (void)ws_size;
    const float* vol   = (const float*)d_in[0];
    const float* Rm    = (const float*)d_in[1];
    const float* Tv    = (const float*)d_in[2];
    const float* focal = (const float*)d_in[3];
    float* out = (float*)d_out;
    float* blkmax = (float*)d_ws;

    dim3 rblock(TPX, CPR, 1);
    dim3 rgrid(IMG_W / TPX, IMG_H, 1);
    render_kernel<<<rgrid, rblock, 0, stream>>>(vol, Rm, Tv, focal, out, blkmax);

    normalize_kernel<<<(IMG_W * IMG_H / 4) / 256, 256, 0, stream>>>(out, blkmax);
}